// Round 10
// baseline (140.523 us; speedup 1.0000x reference)
//
#include <hip/hip_runtime.h>

// xDeepFM CIN, MI355X (gfx950) — R18: FUSED. cin_out + pW eliminated.
// R17 post-mortem: 4 waves/SIMD in cin_out exactly neutral (132.27 vs
// 132.26). Residual-77us ledger: occupancy x2 null, XCD remap null, TLP x2
// null; only B-coalescing (-8us) ever helped => bottleneck is the fresh-pW
// write->read round trip itself (dirty-L2/L3 latency, MSHR-capped).
// R18: out[b] = Wo @ p[b] is batch-local => compute it IN cin_h as a VALU
// matvec (fdot2) over the block's 4 batches. p lives in LDS only:
//   smem f16 layout: hL @0 (18432) | p0 @18432 +b*1024 | p1 @22528 +b*2048
//   p2[b] -> hL[b][0..2047] (written after its h2 reads; disjoint ranges,
//   read-before-write in program order). 61440 B static LDS, 2 blocks/CU.
// Matvec: wave w = kk-quarter, all 4 batches; W frags read once per block
// (896KB, L2-resident); p broadcast from LDS; 8-partial reduce reuses hL.
// Deletes: 20MB pW write, 20MB dirty read, kernel-2 launch.
// h-chain (R10/R13 verified structure) and prep_frag unchanged.

typedef _Float16 f16;
typedef _Float16 f16x2 __attribute__((ext_vector_type(2)));
typedef _Float16 f16x4 __attribute__((ext_vector_type(4)));
typedef _Float16 f16x8 __attribute__((ext_vector_type(8)));
typedef float f32x4 __attribute__((ext_vector_type(4)));
typedef float f32x16 __attribute__((ext_vector_type(16)));

#define HSTR 72      // h LDS row stride (f16): 144B = 9*16B, b128-aligned
#define HB   4608    // per-batch hL region (64*HSTR f16)
#define P0O  18432   // p0 base (f16 offset in smem), +b*1024
#define P1O  22528   // p1 base, +b*2048

__device__ __forceinline__ f32x16 zero16() {
    f32x16 v;
#pragma unroll
    for (int i = 0; i < 16; ++i) v[i] = 0.0f;
    return v;
}

// ---------------- prep: W (fp32 row-major) -> f16 fragment-ordered ----------
// Fragment (mc, kk) = 512 f16; element lane*8+i =
//   W[rbase + mc*32 + (lane&31)][kk*16 + (lane>>5)*8 + i]
// Regions (f16 offsets): H0@0 (W0 r0..63, KK=64) | O0@65536 (W0 r64..127) |
// H1@131072 (W1 r0..63, KK=128) | O1@262144 (W1 r64..127) | O2@393216 (W2 all).
__global__ void __launch_bounds__(256)
prep_frag(const float* __restrict__ W0, const float* __restrict__ W1,
          const float* __restrict__ W2, f16* __restrict__ dst)
{
    int g = (blockIdx.x * 256 + threadIdx.x) * 8;    // grid = 320
    const float* src; int base, KK, rbase;
    if (g < 65536)       { src = W0; base = 0;      KK = 64;  rbase = 0;  }
    else if (g < 131072) { src = W0; base = 65536;  KK = 64;  rbase = 64; }
    else if (g < 262144) { src = W1; base = 131072; KK = 128; rbase = 0;  }
    else if (g < 393216) { src = W1; base = 262144; KK = 128; rbase = 64; }
    else                 { src = W2; base = 393216; KK = 128; rbase = 0;  }
    int local = g - base;
    int frag  = local >> 9;
    int lane  = (local >> 3) & 63;
    int kk    = frag % KK;
    int mc    = frag / KK;
    int row   = rbase + mc * 32 + (lane & 31);
    int col   = kk * 16 + (lane >> 5) * 8;
    int IC    = KK * 16;
    const float* s = src + (size_t)row * IC + col;
    f16x8 o;
#pragma unroll
    for (int i = 0; i < 8; ++i) o[i] = (f16)s[i];
    *(f16x8*)(dst + g) = o;
}

// ---- p-chunk: P rows [jb, jb+32) of one batch -> LINEAR LDS p[j*32+z] -----
// hrows pre-offset to row jb. All LDS reads precede writes (program order).
__device__ __forceinline__ void p_chunk(const f16* __restrict__ hrows,
                                        const f16x8 (&pB)[4],
                                        f16* __restrict__ pdst, int jb,
                                        int t, int q)
{
    f32x16 acc = zero16();
#pragma unroll
    for (int s = 0; s < 4; ++s) {
        f16x8 a = *(const f16x8*)(hrows + t * HSTR + s * 16 + q * 8);
        acc = __builtin_amdgcn_mfma_f32_32x32x16_f16(a, pB[s], acc, 0, 0, 0);
    }
#pragma unroll
    for (int r = 0; r < 16; ++r) {
        int j = jb + (r & 3) + 8 * (r >> 2) + 4 * q;
        pdst[j * 32 + t] = (f16)acc[r];     // k = j*32 + z, z = t
    }
}

// ---- h-GEMM: rows [g*32,+32), ALL 64 cols, TWO batches ---------------------
template <int HJ>
__device__ __forceinline__ void h_gemm4(const f16* __restrict__ Hf,
                                        const f16* __restrict__ h0,
                                        const f16* __restrict__ h1,
                                        int lane8, int t,
                                        const f16x8 (&ip)[2][2][2],   // [b][kq][nh]
                                        f32x16 (&acc)[2][2])          // [b][nh]
{
    acc[0][0] = zero16(); acc[0][1] = zero16();
    acc[1][0] = zero16(); acc[1][1] = zero16();
    const f16* Wp = Hf + lane8;
    f16x8 wf[2][2];   // [phase][kq]
    f16   sc[2][4];   // [phase][b*2+nh]
#pragma unroll
    for (int ph = 0; ph < 2; ++ph) {
        wf[ph][0] = *(const f16x8*)(Wp + (ph * 2 + 0) * 512);
        wf[ph][1] = *(const f16x8*)(Wp + (ph * 2 + 1) * 512);
        sc[ph][0] = h0[ph * HSTR + t];
        sc[ph][1] = h0[ph * HSTR + 32 + t];
        sc[ph][2] = h1[ph * HSTR + t];
        sc[ph][3] = h1[ph * HSTR + 32 + t];
    }
    for (int jj = 0; jj < HJ; jj += 2) {
#pragma unroll
        for (int ph = 0; ph < 2; ++ph) {
            f16x8 w0 = wf[ph][0], w1 = wf[ph][1];
            f16 s00 = sc[ph][0], s01 = sc[ph][1];
            f16 s10 = sc[ph][2], s11 = sc[ph][3];
            int jn = jj + ph + 2;
            if (jn > HJ - 1) jn = HJ - 1;              // clamped refill
            wf[ph][0] = *(const f16x8*)(Wp + (jn * 2 + 0) * 512);
            wf[ph][1] = *(const f16x8*)(Wp + (jn * 2 + 1) * 512);
            sc[ph][0] = h0[jn * HSTR + t];
            sc[ph][1] = h0[jn * HSTR + 32 + t];
            sc[ph][2] = h1[jn * HSTR + t];
            sc[ph][3] = h1[jn * HSTR + 32 + t];
            acc[0][0] = __builtin_amdgcn_mfma_f32_32x32x16_f16(w0, ip[0][0][0] * s00, acc[0][0], 0, 0, 0);
            acc[0][0] = __builtin_amdgcn_mfma_f32_32x32x16_f16(w1, ip[0][1][0] * s00, acc[0][0], 0, 0, 0);
            acc[0][1] = __builtin_amdgcn_mfma_f32_32x32x16_f16(w0, ip[0][0][1] * s01, acc[0][1], 0, 0, 0);
            acc[0][1] = __builtin_amdgcn_mfma_f32_32x32x16_f16(w1, ip[0][1][1] * s01, acc[0][1], 0, 0, 0);
            acc[1][0] = __builtin_amdgcn_mfma_f32_32x32x16_f16(w0, ip[1][0][0] * s10, acc[1][0], 0, 0, 0);
            acc[1][0] = __builtin_amdgcn_mfma_f32_32x32x16_f16(w1, ip[1][1][0] * s10, acc[1][0], 0, 0, 0);
            acc[1][1] = __builtin_amdgcn_mfma_f32_32x32x16_f16(w0, ip[1][0][1] * s11, acc[1][1], 0, 0, 0);
            acc[1][1] = __builtin_amdgcn_mfma_f32_32x32x16_f16(w1, ip[1][1][1] * s11, acc[1][1], 0, 0, 0);
        }
    }
}

__device__ __forceinline__ void load_bias(const float* __restrict__ bl,
                                          float (&bve)[16], int g, int q)
{
#pragma unroll
    for (int r = 0; r < 16; ++r)
        bve[r] = bl[g * 32 + (r & 3) + 8 * (r >> 2) + 4 * q];
}

__device__ __forceinline__ void epi4(const f32x16 (&acc)[2][2],
                                     f16* __restrict__ h0d, f16* __restrict__ h1d,
                                     const float (&bve)[16], int g, int t, int q)
{
#pragma unroll
    for (int r = 0; r < 16; ++r) {
        int row = g * 32 + (r & 3) + 8 * (r >> 2) + 4 * q;
        h0d[row * HSTR + t]      = (f16)(acc[0][0][r] + bve[r]);
        h0d[row * HSTR + 32 + t] = (f16)(acc[0][1][r] + bve[r]);
        h1d[row * HSTR + t]      = (f16)(acc[1][0][r] + bve[r]);
        h1d[row * HSTR + 32 + t] = (f16)(acc[1][1][r] + bve[r]);
    }
}

// ---- matvec over one out-W region: wave handles kk in [kk0, kk0+KKQ) -------
// acc[b][rgb+mc] += sum_i W[rbase+mc*32+(l&31)][kk*16+(l>>5)*8+i] * p[b][...]
template <int KK, int MC, int KKQ>
__device__ __forceinline__ void mv_region(const f16* __restrict__ Of,
                                          const f16* __restrict__ pL, int pStride,
                                          int kk0, int lane,
                                          float (&acc)[4][8], int rgb)
{
    const int half8 = (lane >> 5) * 8;
    const f16* Wp = Of + lane * 8;
#pragma unroll 2
    for (int kk = kk0; kk < kk0 + KKQ; ++kk) {
        f16x8 ps[4];
#pragma unroll
        for (int b = 0; b < 4; ++b)
            ps[b] = *(const f16x8*)(pL + b * pStride + kk * 16 + half8);
#pragma unroll
        for (int mc = 0; mc < MC; ++mc) {
            f16x8 wf = *(const f16x8*)(Wp + (size_t)(mc * KK + kk) * 512);
#pragma unroll
            for (int b = 0; b < 4; ++b) {
#if __has_builtin(__builtin_amdgcn_fdot2)
                const f16x2* w2 = (const f16x2*)&wf;
                const f16x2* p2 = (const f16x2*)&ps[b];
                float a = acc[b][rgb + mc];
                a = __builtin_amdgcn_fdot2(w2[0], p2[0], a, false);
                a = __builtin_amdgcn_fdot2(w2[1], p2[1], a, false);
                a = __builtin_amdgcn_fdot2(w2[2], p2[2], a, false);
                a = __builtin_amdgcn_fdot2(w2[3], p2[3], a, false);
                acc[b][rgb + mc] = a;
#else
                float a = acc[b][rgb + mc];
#pragma unroll
                for (int i = 0; i < 8; ++i)
                    a = fmaf((float)wf[i], (float)ps[b][i], a);
                acc[b][rgb + mc] = a;
#endif
            }
        }
    }
}

// =================== Fused kernel: h-chain + p + out =======================
__global__ void __launch_bounds__(256, 2)
cin_h(const float* __restrict__ inp, const f16* __restrict__ Wf,
      const float* __restrict__ b0v, const float* __restrict__ b1v,
      const float* __restrict__ b2v, float* __restrict__ out)
{
    __shared__ __attribute__((aligned(16))) f16 smem[30720];  // 61440 B

    const int tid   = threadIdx.x;
    const int w     = tid >> 6;
    const int lane  = tid & 63;
    const int t     = lane & 31;
    const int q     = lane >> 5;
    const int lane8 = lane * 8;
    const int bp    = w & 1;          // batch-pair (local batches bp*2, bp*2+1)
    const int g     = w >> 1;         // row-half
    const int b0i   = blockIdx.x * 4;
    f16* hL = smem;

    // Stage: 4 batches x 32 z-rows of inp (f32 coalesced) -> hL rows 0..31.
#pragma unroll
    for (int it = 0; it < 8; ++it) {
        int idx = it * 1024 + tid * 4;
        int b = idx >> 11, rem = idx & 2047;
        int z = rem >> 6, k = rem & 63;
        f32x4 v = *(const f32x4*)(inp + (size_t)(b0i + b) * 2048 + rem);
        f16x4 h4;
        h4[0] = (f16)v[0]; h4[1] = (f16)v[1]; h4[2] = (f16)v[2]; h4[3] = (f16)v[3];
        *(f16x4*)(hL + b * HB + z * HSTR + k) = h4;
    }
    __syncthreads();                                   // B0: h0 (=inp) ready

    // ip[b][kq][nh][i] = inp[bp*2+b][z=kq*16+q*8+i][nh*32+t]
    f16x8 ip[2][2][2];
#pragma unroll
    for (int b = 0; b < 2; ++b) {
        const f16* src = hL + (bp * 2 + b) * HB;
#pragma unroll
        for (int kq = 0; kq < 2; ++kq)
#pragma unroll
            for (int nh = 0; nh < 2; ++nh) {
                f16x8 v;
#pragma unroll
                for (int i = 0; i < 8; ++i)
                    v[i] = src[(kq * 16 + q * 8 + i) * HSTR + nh * 32 + t];
                ip[b][kq][nh] = v;
            }
    }
    // pB[s][i] = inp[w][z=t][k=s*16+q*8+i] — p-GEMM B-frags (wave w <-> batch w)
    f16x8 pB[4];
#pragma unroll
    for (int s = 0; s < 4; ++s)
        pB[s] = *(const f16x8*)(hL + w * HB + t * HSTR + s * 16 + q * 8);

    const f16* H0 = Wf;
    const f16* H1 = Wf + 131072;
    f16* hA = hL + (bp * 2) * HB;
    f16* hB2 = hL + (bp * 2 + 1) * HB;
    f32x16 acc[2][2];
    float bve[16];

    // ---- Layer 0 (HJ=32) ----
    p_chunk(hL + w * HB, pB, smem + P0O + w * 1024, 0, t, q);   // p0
    h_gemm4<32>(H0 + g * 64 * 512, hA, hB2, lane8, t, ip, acc);
    load_bias(b0v, bve, g, q);
    __syncthreads();                                   // B1: all h0 reads done
    epi4(acc, hA, hB2, bve, g, t, q);                  // h1 (rows 0..63)
    __syncthreads();                                   // B2: h1 ready

    // ---- Layer 1 (HJ=64) ----
    p_chunk(hL + w * HB,             pB, smem + P1O + w * 2048, 0,  t, q);
    p_chunk(hL + w * HB + 32 * HSTR, pB, smem + P1O + w * 2048, 32, t, q);
    h_gemm4<64>(H1 + g * 128 * 512, hA, hB2, lane8, t, ip, acc);
    load_bias(b1v, bve, g, q);
    __syncthreads();                                   // B3: all h1 reads done
    epi4(acc, hA, hB2, bve, g, t, q);                  // h1 -> h2 in place
    __syncthreads();                                   // B4: h2 ready

    // ---- p2 -> hL[w][0..2047] (reads of h2 precede writes; ranges safe) ----
    p_chunk(hL + w * HB,             pB, hL + w * HB, 0,  t, q);
    p_chunk(hL + w * HB + 32 * HSTR, pB, hL + w * HB, 32, t, q);
    __syncthreads();                                   // B5: all p ready

    // ---- out matvec: wave w = kk-quarter, all 4 batches --------------------
    {
        float acc8[4][8];
#pragma unroll
        for (int b = 0; b < 4; ++b)
#pragma unroll
            for (int rg = 0; rg < 8; ++rg) acc8[b][rg] = 0.0f;

        mv_region<64, 2, 16>(Wf + 65536,  smem + P0O, 1024, w * 16, lane, acc8, 0);
        mv_region<128, 2, 32>(Wf + 262144, smem + P1O, 2048, w * 32, lane, acc8, 2);
        mv_region<128, 4, 32>(Wf + 393216, hL,         HB,   w * 32, lane, acc8, 4);
        __syncthreads();                               // B6: all p reads done

        float* rPf = (float*)smem;                     // 32 KB partials in hL
#pragma unroll
        for (int b = 0; b < 4; ++b)
#pragma unroll
            for (int rg = 0; rg < 8; ++rg)
                rPf[((w * 4 + b) * 8 + rg) * 64 + lane] = acc8[b][rg];
    }
    __syncthreads();                                   // B7: partials ready

    // ---- combine: 1024 outputs = 4 batches x 256 cols ----------------------
    {
        const float* rPf = (const float*)smem;
#pragma unroll
        for (int it = 0; it < 4; ++it) {
            int idx = it * 256 + tid;
            int b   = idx >> 8;
            int rem = idx & 255;
            int rg  = rem >> 5;
            int r32 = rem & 31;
            float s = 0.0f;
#pragma unroll
            for (int wv = 0; wv < 4; ++wv) {
                s += rPf[((wv * 4 + b) * 8 + rg) * 64 + r32];
                s += rPf[((wv * 4 + b) * 8 + rg) * 64 + 32 + r32];
            }
            int col; float bias;
            if (rg < 2)      { col = rg * 32 + r32;           bias = b0v[64 + col]; }
            else if (rg < 4) { col = 64 + (rg - 2) * 32 + r32; bias = b1v[col]; }
            else             { col = 128 + (rg - 4) * 32 + r32; bias = b2v[col - 128]; }
            out[(size_t)(b0i + b) * 256 + col] = s + 64.0f * bias;
        }
    }
}

extern "C" void kernel_launch(void* const* d_in, const int* in_sizes, int n_in,
                              void* d_out, int out_size, void* d_ws, size_t ws_size,
                              hipStream_t stream)
{
    const float* inp = (const float*)d_in[0];
    const float* W0  = (const float*)d_in[1];
    const float* b0  = (const float*)d_in[2];
    const float* W1  = (const float*)d_in[3];
    const float* b1  = (const float*)d_in[4];
    const float* W2  = (const float*)d_in[5];
    const float* b2  = (const float*)d_in[6];
    float* out = (float*)d_out;

    f16* Wf = (f16*)d_ws;             // 655360 f16 = 1.25 MB fragment-ordered

    prep_frag<<<320, 256, 0, stream>>>(W0, W1, W2, Wf);
    cin_h<<<512, 256, 0, stream>>>(inp, Wf, b0, b1, b2, out);
}

// Round 11
// 139.042 us; speedup vs baseline: 1.0107x; 1.0107x over previous
//
#include <hip/hip_runtime.h>

// xDeepFM CIN, MI355X (gfx950) — R19: R13 base + product-pipelined h_gemm4.
// R18 accounting: cin_out was only ~5-9us (removing it cut residual 77->65
// while fused matvec cost +20 in-kernel). Fixed residual ~55-65us = prep +
// launch gaps + harness reset; insensitive to kernel count. R12/R16/R17
// nulls explained: they optimized a ~7us kernel. Reverted to R13 (132.3).
// cin_h (55us, MfmaUtil 42 + VALU 36, neither saturated): per-j VALU->MFMA
// dependency (B-operand built just-in-time) caps both pipes at ~50/50
// cross-wave round-robin. R19: 1-phase-lookahead product pipeline pr[2][8]
// — MFMA(ph) consumes products built last phase; VALU builds pr[ph^1]
// during the MFMA burst. +64 VGPR (112->~176): free, grid=512 caps
// occupancy at 2 blocks/CU anyway. prep/cin_out/pW layout: R13 verbatim.

typedef _Float16 f16;
typedef _Float16 f16x4 __attribute__((ext_vector_type(4)));
typedef _Float16 f16x8 __attribute__((ext_vector_type(8)));
typedef float f32x4 __attribute__((ext_vector_type(4)));
typedef float f32x16 __attribute__((ext_vector_type(16)));

#define HSTR 72      // h LDS row stride (f16): 144B = 9*16B, b128-aligned
#define GSTR 163840  // pW per-32-batch-group stride (f16): 320 frags * 512
#define P0G  0       // p0 frags [0,64)   within group
#define P1G  32768   // p1 frags [0,128)  within group
#define P2G  98304   // p2 frags [0,128)  within group

__device__ __forceinline__ f32x16 zero16() {
    f32x16 v;
#pragma unroll
    for (int i = 0; i < 16; ++i) v[i] = 0.0f;
    return v;
}

// ---------------- prep: W (fp32 row-major) -> f16 fragment-ordered ----------
// Fragment (mc, kk) = 512 f16; element lane*8+i =
//   W[rbase + mc*32 + (lane&31)][kk*16 + (lane>>5)*8 + i]
// Regions (f16 offsets): H0@0 (W0 r0..63, KK=64) | O0@65536 (W0 r64..127) |
// H1@131072 (W1 r0..63, KK=128) | O1@262144 (W1 r64..127) | O2@393216 (W2 all).
__global__ void __launch_bounds__(256)
prep_frag(const float* __restrict__ W0, const float* __restrict__ W1,
          const float* __restrict__ W2, f16* __restrict__ dst)
{
    int g = (blockIdx.x * 256 + threadIdx.x) * 8;    // grid = 320
    const float* src; int base, KK, rbase;
    if (g < 65536)       { src = W0; base = 0;      KK = 64;  rbase = 0;  }
    else if (g < 131072) { src = W0; base = 65536;  KK = 64;  rbase = 64; }
    else if (g < 262144) { src = W1; base = 131072; KK = 128; rbase = 0;  }
    else if (g < 393216) { src = W1; base = 262144; KK = 128; rbase = 64; }
    else                 { src = W2; base = 393216; KK = 128; rbase = 0;  }
    int local = g - base;
    int frag  = local >> 9;
    int lane  = (local >> 3) & 63;
    int kk    = frag % KK;
    int mc    = frag / KK;
    int row   = rbase + mc * 32 + (lane & 31);
    int col   = kk * 16 + (lane >> 5) * 8;
    int IC    = KK * 16;
    const float* s = src + (size_t)row * IC + col;
    f16x8 o;
#pragma unroll
    for (int i = 0; i < 8; ++i) o[i] = (f16)s[i];
    *(f16x8*)(dst + g) = o;
}

// ---- p-chunk: P rows [jb, jb+32) of one batch (M=32 j, N=32 z, K=64) ------
// Writes fragment-ordered: pdst = groupbase + regionoff + (b&31)*8.
__device__ __forceinline__ void p_chunk(const f16* __restrict__ hrows,
                                        const f16x8 (&pB)[4],
                                        f16* __restrict__ pdst, int jb,
                                        int t, int q)
{
    f32x16 acc = zero16();
#pragma unroll
    for (int s = 0; s < 4; ++s) {
        f16x8 a = *(const f16x8*)(hrows + t * HSTR + s * 16 + q * 8);
        acc = __builtin_amdgcn_mfma_f32_32x32x16_f16(a, pB[s], acc, 0, 0, 0);
    }
#pragma unroll
    for (int r = 0; r < 16; ++r) {
        int j = jb + (r & 3) + 8 * (r >> 2) + 4 * q;
        int f = j * 2 + (t >> 4);
        pdst[f * 512 + ((t >> 3) & 1) * 256 + (t & 7)] = (f16)acc[r];
    }
}

// ---- h-GEMM (R19): product-pipelined. pr[ph] = B-operands for j=jj+ph, ----
// built one phase AHEAD so MFMA(ph) never waits on VALU. pr[2][8]:
// index = b*4 + kq*2 + nh. Refill depth-2 ping-pong on wf/sc unchanged.
template <int HJ>
__device__ __forceinline__ void h_gemm4(const f16* __restrict__ Hf,
                                        const f16* __restrict__ h0,
                                        const f16* __restrict__ h1,
                                        int lane8, int t,
                                        const f16x8 (&ip)[2][2][2],   // [b][kq][nh]
                                        f32x16 (&acc)[2][2])          // [b][nh]
{
    acc[0][0] = zero16(); acc[0][1] = zero16();
    acc[1][0] = zero16(); acc[1][1] = zero16();
    const f16* Wp = Hf + lane8;
    f16x8 wf[2][2];   // [phase][kq]
    f16   sc[2][4];   // [phase][b*2+nh]
    f16x8 pr[2][8];   // [phase][b*4+kq*2+nh]
#pragma unroll
    for (int ph = 0; ph < 2; ++ph) {
        wf[ph][0] = *(const f16x8*)(Wp + (ph * 2 + 0) * 512);
        wf[ph][1] = *(const f16x8*)(Wp + (ph * 2 + 1) * 512);
        sc[ph][0] = h0[ph * HSTR + t];
        sc[ph][1] = h0[ph * HSTR + 32 + t];
        sc[ph][2] = h1[ph * HSTR + t];
        sc[ph][3] = h1[ph * HSTR + 32 + t];
    }
    // build pr[0] (products for j=0)
    pr[0][0] = ip[0][0][0] * sc[0][0];  pr[0][1] = ip[0][0][1] * sc[0][1];
    pr[0][2] = ip[0][1][0] * sc[0][0];  pr[0][3] = ip[0][1][1] * sc[0][1];
    pr[0][4] = ip[1][0][0] * sc[0][2];  pr[0][5] = ip[1][0][1] * sc[0][3];
    pr[0][6] = ip[1][1][0] * sc[0][2];  pr[0][7] = ip[1][1][1] * sc[0][3];

    for (int jj = 0; jj < HJ; jj += 2) {
#pragma unroll
        for (int ph = 0; ph < 2; ++ph) {
            const int po = ph ^ 1;
            f16x8 w0 = wf[ph][0], w1 = wf[ph][1];
            int jn = jj + ph + 2;
            if (jn > HJ - 1) jn = HJ - 1;              // clamped refill
            wf[ph][0] = *(const f16x8*)(Wp + (jn * 2 + 0) * 512);
            wf[ph][1] = *(const f16x8*)(Wp + (jn * 2 + 1) * 512);
            sc[ph][0] = h0[jn * HSTR + t];
            sc[ph][1] = h0[jn * HSTR + 32 + t];
            sc[ph][2] = h1[jn * HSTR + t];
            sc[ph][3] = h1[jn * HSTR + 32 + t];
            // MFMAs consume pre-built pr[ph]; same-acc pairs spaced 4 apart.
            acc[0][0] = __builtin_amdgcn_mfma_f32_32x32x16_f16(w0, pr[ph][0], acc[0][0], 0, 0, 0);
            acc[0][1] = __builtin_amdgcn_mfma_f32_32x32x16_f16(w0, pr[ph][1], acc[0][1], 0, 0, 0);
            acc[1][0] = __builtin_amdgcn_mfma_f32_32x32x16_f16(w0, pr[ph][4], acc[1][0], 0, 0, 0);
            acc[1][1] = __builtin_amdgcn_mfma_f32_32x32x16_f16(w0, pr[ph][5], acc[1][1], 0, 0, 0);
            acc[0][0] = __builtin_amdgcn_mfma_f32_32x32x16_f16(w1, pr[ph][2], acc[0][0], 0, 0, 0);
            acc[0][1] = __builtin_amdgcn_mfma_f32_32x32x16_f16(w1, pr[ph][3], acc[0][1], 0, 0, 0);
            acc[1][0] = __builtin_amdgcn_mfma_f32_32x32x16_f16(w1, pr[ph][6], acc[1][0], 0, 0, 0);
            acc[1][1] = __builtin_amdgcn_mfma_f32_32x32x16_f16(w1, pr[ph][7], acc[1][1], 0, 0, 0);
            // build pr[po] for j = jj+ph+1 from sc[po] (overlaps MFMA burst;
            // at ph=1, sc[0] was refilled during ph=0 to j=jj+2 — correct).
            pr[po][0] = ip[0][0][0] * sc[po][0];  pr[po][1] = ip[0][0][1] * sc[po][1];
            pr[po][2] = ip[0][1][0] * sc[po][0];  pr[po][3] = ip[0][1][1] * sc[po][1];
            pr[po][4] = ip[1][0][0] * sc[po][2];  pr[po][5] = ip[1][0][1] * sc[po][3];
            pr[po][6] = ip[1][1][0] * sc[po][2];  pr[po][7] = ip[1][1][1] * sc[po][3];
        }
    }
}

__device__ __forceinline__ void load_bias(const float* __restrict__ bl,
                                          float (&bve)[16], int g, int q)
{
#pragma unroll
    for (int r = 0; r < 16; ++r)
        bve[r] = bl[g * 32 + (r & 3) + 8 * (r >> 2) + 4 * q];
}

// Write h_{l+1} rows [g*32,+32), all 64 cols, both batches.
__device__ __forceinline__ void epi4(const f32x16 (&acc)[2][2],
                                     f16* __restrict__ h0d, f16* __restrict__ h1d,
                                     const float (&bve)[16], int g, int t, int q)
{
#pragma unroll
    for (int r = 0; r < 16; ++r) {
        int row = g * 32 + (r & 3) + 8 * (r >> 2) + 4 * q;
        h0d[row * HSTR + t]      = (f16)(acc[0][0][r] + bve[r]);
        h0d[row * HSTR + 32 + t] = (f16)(acc[0][1][r] + bve[r]);
        h1d[row * HSTR + t]      = (f16)(acc[1][0][r] + bve[r]);
        h1d[row * HSTR + 32 + t] = (f16)(acc[1][1][r] + bve[r]);
    }
}

// =================== Kernel 1: h-chain + p-vectors =========================
__global__ void __launch_bounds__(256, 2)
cin_h(const float* __restrict__ inp, const f16* __restrict__ Wf,
      f16* __restrict__ pW,
      const float* __restrict__ b0v, const float* __restrict__ b1v)
{
    __shared__ __attribute__((aligned(16))) f16 hL[4 * 64 * HSTR];  // 36864 B

    const int tid   = threadIdx.x;
    const int w     = tid >> 6;
    const int lane  = tid & 63;
    const int t     = lane & 31;
    const int q     = lane >> 5;
    const int lane8 = lane * 8;
    const int bp    = w & 1;          // batch-pair (local batches bp*2, bp*2+1)
    const int g     = w >> 1;         // row-half
    const int b0i   = blockIdx.x * 4;

    // Stage: 4 batches x 32 z-rows of inp (f32 coalesced) -> hL rows 0..31.
#pragma unroll
    for (int it = 0; it < 8; ++it) {
        int idx = it * 1024 + tid * 4;
        int b = idx >> 11, rem = idx & 2047;
        int z = rem >> 6, k = rem & 63;
        f32x4 v = *(const f32x4*)(inp + (size_t)(b0i + b) * 2048 + rem);
        f16x4 h4;
        h4[0] = (f16)v[0]; h4[1] = (f16)v[1]; h4[2] = (f16)v[2]; h4[3] = (f16)v[3];
        *(f16x4*)(hL + b * 64 * HSTR + z * HSTR + k) = h4;
    }
    __syncthreads();                                   // B0: h0 (=inp) ready

    // ip[b][kq][nh][i] = inp[bp*2+b][z=kq*16+q*8+i][nh*32+t]
    f16x8 ip[2][2][2];
#pragma unroll
    for (int b = 0; b < 2; ++b) {
        const f16* src = hL + (bp * 2 + b) * 64 * HSTR;
#pragma unroll
        for (int kq = 0; kq < 2; ++kq)
#pragma unroll
            for (int nh = 0; nh < 2; ++nh) {
                f16x8 v;
#pragma unroll
                for (int i = 0; i < 8; ++i)
                    v[i] = src[(kq * 16 + q * 8 + i) * HSTR + nh * 32 + t];
                ip[b][kq][nh] = v;
            }
    }
    // pB[s][i] = inp[w][z=t][k=s*16+q*8+i] — p-GEMM B-frags (wave w <-> batch w)
    f16x8 pB[4];
#pragma unroll
    for (int s = 0; s < 4; ++s)
        pB[s] = *(const f16x8*)(hL + w * 64 * HSTR + t * HSTR + s * 16 + q * 8);

    const int bglob = b0i + w;        // wave w <-> batch w (p-work)
    f16* pG = pW + (size_t)(bglob >> 5) * GSTR + (bglob & 31) * 8;
    const f16* H0 = Wf;
    const f16* H1 = Wf + 131072;
    f16* hA = hL + (bp * 2) * 64 * HSTR;
    f16* hB = hL + (bp * 2 + 1) * 64 * HSTR;
    f32x16 acc[2][2];
    float bve[16];

    // ---- Layer 0 (HJ=32) ----
    p_chunk(hL + w * 64 * HSTR, pB, pG + P0G, 0, t, q);     // p0 j 0..31
    h_gemm4<32>(H0 + g * 64 * 512, hA, hB, lane8, t, ip, acc);
    load_bias(b0v, bve, g, q);
    __syncthreads();                                   // B1: all h0 reads done
    epi4(acc, hA, hB, bve, g, t, q);                   // h1 (rows 0..63)
    __syncthreads();                                   // B2: h1 ready

    // ---- Layer 1 (HJ=64) ----
    p_chunk(hL + w * 64 * HSTR,             pB, pG + P1G, 0,  t, q);
    p_chunk(hL + w * 64 * HSTR + 32 * HSTR, pB, pG + P1G, 32, t, q);
    h_gemm4<64>(H1 + g * 128 * 512, hA, hB, lane8, t, ip, acc);
    load_bias(b1v, bve, g, q);
    __syncthreads();                                   // B3: all h1 reads done
    epi4(acc, hA, hB, bve, g, t, q);                   // h1 -> h2 in place
    __syncthreads();                                   // B4: h2 ready

    p_chunk(hL + w * 64 * HSTR,             pB, pG + P2G, 0,  t, q);
    p_chunk(hL + w * 64 * HSTR + 32 * HSTR, pB, pG + P2G, 32, t, q);
}

// =================== Kernel 2: out GEMMs (N = batch), R13 ==================
// Block = 512 thr (8 waves): mi = M-half, ki = K-quarter. B-frags 1KB
// wave-coalesced (fragment-ordered pW); mi-pair reads identical addresses
// (L1 share). Depth-8 prefetch ring. 4-way K partials reduced via 32KB LDS.
template <int KK>   // KK = total K-fragments (region0: 64, others: 128)
__device__ __forceinline__ void o_tile(const f16* __restrict__ Of,
                                       const f16* __restrict__ pBase,
                                       const float* __restrict__ biasp,
                                       float* __restrict__ out,
                                       float* __restrict__ rP,
                                       int bg, int colbase, int tid)
{
    const int w = tid >> 6, lane = tid & 63, t = lane & 31, q = lane >> 5;
    const int lane8 = lane * 8;
    const int mi = w & 1, ki = w >> 1;           // mi pairs adjacent -> B share
    const int SQ = KK / 4;                       // K-frags per wave (16 or 32)
    const f16* Ap = Of + (size_t)(mi * KK + ki * SQ) * 512 + lane8;
    const f16* Bp = pBase + (size_t)(ki * SQ) * 512 + lane8;

    f32x16 acc = zero16();
    f16x8 af[8], bf[8];
#pragma unroll
    for (int i = 0; i < 8; ++i) {
        af[i] = *(const f16x8*)(Ap + i * 512);
        bf[i] = *(const f16x8*)(Bp + i * 512);
    }
#pragma unroll 8
    for (int s = 0; s < SQ; ++s) {
        int idx = s & 7;
        f16x8 a = af[idx], b = bf[idx];
        int sn = s + 8 < SQ ? s + 8 : SQ - 1;    // clamped refill
        af[idx] = *(const f16x8*)(Ap + sn * 512);
        bf[idx] = *(const f16x8*)(Bp + sn * 512);
        acc = __builtin_amdgcn_mfma_f32_32x32x16_f16(a, b, acc, 0, 0, 0);
    }
#pragma unroll
    for (int r = 0; r < 16; ++r) {
        int m = mi * 32 + (r & 3) + 8 * (r >> 2) + 4 * q;
        rP[(ki * 32 + t) * 64 + m] = acc[r];
    }
    __syncthreads();
    // Combine: 512 thr x f32x4 = 2048 f32 (32 batches x 64 cols).
    {
        int n = tid >> 4;            // batch row 0..31
        int o = (tid & 15) * 4;      // col 0..60
        f32x4 v = *(const f32x4*)(rP + n * 64 + o);
#pragma unroll
        for (int k2 = 1; k2 < 4; ++k2) {
            f32x4 u = *(const f32x4*)(rP + (k2 * 32 + n) * 64 + o);
            v[0] += u[0]; v[1] += u[1]; v[2] += u[2]; v[3] += u[3];
        }
        f32x4 bb = *(const f32x4*)(biasp + o);
        v[0] += 64.0f * bb[0]; v[1] += 64.0f * bb[1];
        v[2] += 64.0f * bb[2]; v[3] += 64.0f * bb[3];
        *(f32x4*)(out + (size_t)(bg * 32 + n) * 256 + colbase + o) = v;
    }
}

__global__ void __launch_bounds__(512, 2)
cin_out(const f16* __restrict__ Wf, const f16* __restrict__ pW,
        const float* __restrict__ b0v, const float* __restrict__ b1v,
        const float* __restrict__ b2v, float* __restrict__ out)
{
    __shared__ __attribute__((aligned(16))) float rP[4 * 32 * 64];  // 32 KB
    const int tid = threadIdx.x;
    const int r  = blockIdx.x & 3;      // region
    const int bg = blockIdx.x >> 2;     // 32-batch group (64 of them)
    const f16* pGrp = pW + (size_t)bg * GSTR;
    if (r == 0)
        o_tile<64> (Wf + 65536,  pGrp + P0G, b0v + 64, out, rP, bg, 0,   tid);
    else if (r == 1)
        o_tile<128>(Wf + 262144, pGrp + P1G, b1v + 64, out, rP, bg, 64,  tid);
    else if (r == 2)
        o_tile<128>(Wf + 393216, pGrp + P2G, b2v,      out, rP, bg, 128, tid);
    else
        o_tile<128>(Wf + 524288, pGrp + P2G, b2v + 64, out, rP, bg, 192, tid);
}

extern "C" void kernel_launch(void* const* d_in, const int* in_sizes, int n_in,
                              void* d_out, int out_size, void* d_ws, size_t ws_size,
                              hipStream_t stream)
{
    const float* inp = (const float*)d_in[0];
    const float* W0  = (const float*)d_in[1];
    const float* b0  = (const float*)d_in[2];
    const float* W1  = (const float*)d_in[3];
    const float* b1  = (const float*)d_in[4];
    const float* W2  = (const float*)d_in[5];
    const float* b2  = (const float*)d_in[6];
    float* out = (float*)d_out;

    f16* Wf = (f16*)d_ws;             // 655360 f16 = 1.25 MB fragment-ordered
    f16* pW = Wf + 655360;            // 64 groups * 163840 f16 = 20 MB

    prep_frag<<<320, 256, 0, stream>>>(W0, W1, W2, Wf);
    cin_h<<<512, 256, 0, stream>>>(inp, Wf, pW, b0, b1);
    cin_out<<<256, 512, 0, stream>>>(Wf, pW, b0, b1, b2, out);
}

// Round 12
// 134.435 us; speedup vs baseline: 1.0453x; 1.0343x over previous
//
#include <hip/hip_runtime.h>

// xDeepFM CIN, MI355X (gfx950) — R20: R13 verbatim + s_setprio(T5) on h MFMAs.
// R19 post-mortem: explicit product pipeline regressed cin_h 55->71
// (MfmaUtil 42->31, VGPR 112->100): compiler's natural R10 schedule was
// already optimal; 5/5 manual restructures lost. Model: MFMA floor 21.2us
// = 38.5% of 55us wall (matches 42% measured); VALU 20us is sc-u16 reads +
// epi/p_chunk scalar traffic, not just products; pipes overlap ~78%.
// R20 = R13 + runtime-only wave-arbitration hint: setprio(1) around the
// 8-MFMA cluster (waves drift between layer barriers => role diversity,
// the T5-positive regime per m191). No instruction reordering.

typedef _Float16 f16;
typedef _Float16 f16x4 __attribute__((ext_vector_type(4)));
typedef _Float16 f16x8 __attribute__((ext_vector_type(8)));
typedef float f32x4 __attribute__((ext_vector_type(4)));
typedef float f32x16 __attribute__((ext_vector_type(16)));

#define HSTR 72      // h LDS row stride (f16): 144B = 9*16B, b128-aligned
#define GSTR 163840  // pW per-32-batch-group stride (f16): 320 frags * 512
#define P0G  0       // p0 frags [0,64)   within group
#define P1G  32768   // p1 frags [0,128)  within group
#define P2G  98304   // p2 frags [0,128)  within group

__device__ __forceinline__ f32x16 zero16() {
    f32x16 v;
#pragma unroll
    for (int i = 0; i < 16; ++i) v[i] = 0.0f;
    return v;
}

// ---------------- prep: W (fp32 row-major) -> f16 fragment-ordered ----------
// Fragment (mc, kk) = 512 f16; element lane*8+i =
//   W[rbase + mc*32 + (lane&31)][kk*16 + (lane>>5)*8 + i]
// Regions (f16 offsets): H0@0 (W0 r0..63, KK=64) | O0@65536 (W0 r64..127) |
// H1@131072 (W1 r0..63, KK=128) | O1@262144 (W1 r64..127) | O2@393216 (W2 all).
__global__ void __launch_bounds__(256)
prep_frag(const float* __restrict__ W0, const float* __restrict__ W1,
          const float* __restrict__ W2, f16* __restrict__ dst)
{
    int g = (blockIdx.x * 256 + threadIdx.x) * 8;    // grid = 320
    const float* src; int base, KK, rbase;
    if (g < 65536)       { src = W0; base = 0;      KK = 64;  rbase = 0;  }
    else if (g < 131072) { src = W0; base = 65536;  KK = 64;  rbase = 64; }
    else if (g < 262144) { src = W1; base = 131072; KK = 128; rbase = 0;  }
    else if (g < 393216) { src = W1; base = 262144; KK = 128; rbase = 64; }
    else                 { src = W2; base = 393216; KK = 128; rbase = 0;  }
    int local = g - base;
    int frag  = local >> 9;
    int lane  = (local >> 3) & 63;
    int kk    = frag % KK;
    int mc    = frag / KK;
    int row   = rbase + mc * 32 + (lane & 31);
    int col   = kk * 16 + (lane >> 5) * 8;
    int IC    = KK * 16;
    const float* s = src + (size_t)row * IC + col;
    f16x8 o;
#pragma unroll
    for (int i = 0; i < 8; ++i) o[i] = (f16)s[i];
    *(f16x8*)(dst + g) = o;
}

// ---- p-chunk: P rows [jb, jb+32) of one batch (M=32 j, N=32 z, K=64) ------
// Writes fragment-ordered: pdst = groupbase + regionoff + (b&31)*8.
__device__ __forceinline__ void p_chunk(const f16* __restrict__ hrows,
                                        const f16x8 (&pB)[4],
                                        f16* __restrict__ pdst, int jb,
                                        int t, int q)
{
    f32x16 acc = zero16();
#pragma unroll
    for (int s = 0; s < 4; ++s) {
        f16x8 a = *(const f16x8*)(hrows + t * HSTR + s * 16 + q * 8);
        acc = __builtin_amdgcn_mfma_f32_32x32x16_f16(a, pB[s], acc, 0, 0, 0);
    }
#pragma unroll
    for (int r = 0; r < 16; ++r) {
        int j = jb + (r & 3) + 8 * (r >> 2) + 4 * q;
        int f = j * 2 + (t >> 4);
        pdst[f * 512 + ((t >> 3) & 1) * 256 + (t & 7)] = (f16)acc[r];
    }
}

// ---- h-GEMM: rows [g*32,+32), ALL 64 cols, TWO batches ---------------------
// Per j: 2 W-frag loads feed 8 MFMAs (258 SIMD-cyc window > L2 latency).
// Ping-pong depth-2 (j, j+1 resident; refill j+2). setprio(1) wraps the
// MFMA cluster: CU favors MFMA-phase waves over load-phase waves (T5).
template <int HJ>
__device__ __forceinline__ void h_gemm4(const f16* __restrict__ Hf,
                                        const f16* __restrict__ h0,
                                        const f16* __restrict__ h1,
                                        int lane8, int t,
                                        const f16x8 (&ip)[2][2][2],   // [b][kq][nh]
                                        f32x16 (&acc)[2][2])          // [b][nh]
{
    acc[0][0] = zero16(); acc[0][1] = zero16();
    acc[1][0] = zero16(); acc[1][1] = zero16();
    const f16* Wp = Hf + lane8;
    f16x8 wf[2][2];   // [phase][kq]
    f16   sc[2][4];   // [phase][b*2+nh]
#pragma unroll
    for (int ph = 0; ph < 2; ++ph) {
        wf[ph][0] = *(const f16x8*)(Wp + (ph * 2 + 0) * 512);
        wf[ph][1] = *(const f16x8*)(Wp + (ph * 2 + 1) * 512);
        sc[ph][0] = h0[ph * HSTR + t];
        sc[ph][1] = h0[ph * HSTR + 32 + t];
        sc[ph][2] = h1[ph * HSTR + t];
        sc[ph][3] = h1[ph * HSTR + 32 + t];
    }
    for (int jj = 0; jj < HJ; jj += 2) {
#pragma unroll
        for (int ph = 0; ph < 2; ++ph) {
            f16x8 w0 = wf[ph][0], w1 = wf[ph][1];
            f16 s00 = sc[ph][0], s01 = sc[ph][1];
            f16 s10 = sc[ph][2], s11 = sc[ph][3];
            int jn = jj + ph + 2;
            if (jn > HJ - 1) jn = HJ - 1;              // clamped refill
            wf[ph][0] = *(const f16x8*)(Wp + (jn * 2 + 0) * 512);
            wf[ph][1] = *(const f16x8*)(Wp + (jn * 2 + 1) * 512);
            sc[ph][0] = h0[jn * HSTR + t];
            sc[ph][1] = h0[jn * HSTR + 32 + t];
            sc[ph][2] = h1[jn * HSTR + t];
            sc[ph][3] = h1[jn * HSTR + 32 + t];
            __builtin_amdgcn_s_setprio(1);
            acc[0][0] = __builtin_amdgcn_mfma_f32_32x32x16_f16(w0, ip[0][0][0] * s00, acc[0][0], 0, 0, 0);
            acc[0][0] = __builtin_amdgcn_mfma_f32_32x32x16_f16(w1, ip[0][1][0] * s00, acc[0][0], 0, 0, 0);
            acc[0][1] = __builtin_amdgcn_mfma_f32_32x32x16_f16(w0, ip[0][0][1] * s01, acc[0][1], 0, 0, 0);
            acc[0][1] = __builtin_amdgcn_mfma_f32_32x32x16_f16(w1, ip[0][1][1] * s01, acc[0][1], 0, 0, 0);
            acc[1][0] = __builtin_amdgcn_mfma_f32_32x32x16_f16(w0, ip[1][0][0] * s10, acc[1][0], 0, 0, 0);
            acc[1][0] = __builtin_amdgcn_mfma_f32_32x32x16_f16(w1, ip[1][1][0] * s10, acc[1][0], 0, 0, 0);
            acc[1][1] = __builtin_amdgcn_mfma_f32_32x32x16_f16(w0, ip[1][0][1] * s11, acc[1][1], 0, 0, 0);
            acc[1][1] = __builtin_amdgcn_mfma_f32_32x32x16_f16(w1, ip[1][1][1] * s11, acc[1][1], 0, 0, 0);
            __builtin_amdgcn_s_setprio(0);
        }
    }
}

__device__ __forceinline__ void load_bias(const float* __restrict__ bl,
                                          float (&bve)[16], int g, int q)
{
#pragma unroll
    for (int r = 0; r < 16; ++r)
        bve[r] = bl[g * 32 + (r & 3) + 8 * (r >> 2) + 4 * q];
}

// Write h_{l+1} rows [g*32,+32), all 64 cols, both batches.
__device__ __forceinline__ void epi4(const f32x16 (&acc)[2][2],
                                     f16* __restrict__ h0d, f16* __restrict__ h1d,
                                     const float (&bve)[16], int g, int t, int q)
{
#pragma unroll
    for (int r = 0; r < 16; ++r) {
        int row = g * 32 + (r & 3) + 8 * (r >> 2) + 4 * q;
        h0d[row * HSTR + t]      = (f16)(acc[0][0][r] + bve[r]);
        h0d[row * HSTR + 32 + t] = (f16)(acc[0][1][r] + bve[r]);
        h1d[row * HSTR + t]      = (f16)(acc[1][0][r] + bve[r]);
        h1d[row * HSTR + 32 + t] = (f16)(acc[1][1][r] + bve[r]);
    }
}

// =================== Kernel 1: h-chain + p-vectors =========================
__global__ void __launch_bounds__(256, 2)
cin_h(const float* __restrict__ inp, const f16* __restrict__ Wf,
      f16* __restrict__ pW,
      const float* __restrict__ b0v, const float* __restrict__ b1v)
{
    __shared__ __attribute__((aligned(16))) f16 hL[4 * 64 * HSTR];  // 36864 B

    const int tid   = threadIdx.x;
    const int w     = tid >> 6;
    const int lane  = tid & 63;
    const int t     = lane & 31;
    const int q     = lane >> 5;
    const int lane8 = lane * 8;
    const int bp    = w & 1;          // batch-pair (local batches bp*2, bp*2+1)
    const int g     = w >> 1;         // row-half
    const int b0i   = blockIdx.x * 4;

    // Stage: 4 batches x 32 z-rows of inp (f32 coalesced) -> hL rows 0..31.
#pragma unroll
    for (int it = 0; it < 8; ++it) {
        int idx = it * 1024 + tid * 4;
        int b = idx >> 11, rem = idx & 2047;
        int z = rem >> 6, k = rem & 63;
        f32x4 v = *(const f32x4*)(inp + (size_t)(b0i + b) * 2048 + rem);
        f16x4 h4;
        h4[0] = (f16)v[0]; h4[1] = (f16)v[1]; h4[2] = (f16)v[2]; h4[3] = (f16)v[3];
        *(f16x4*)(hL + b * 64 * HSTR + z * HSTR + k) = h4;
    }
    __syncthreads();                                   // B0: h0 (=inp) ready

    // ip[b][kq][nh][i] = inp[bp*2+b][z=kq*16+q*8+i][nh*32+t]
    f16x8 ip[2][2][2];
#pragma unroll
    for (int b = 0; b < 2; ++b) {
        const f16* src = hL + (bp * 2 + b) * 64 * HSTR;
#pragma unroll
        for (int kq = 0; kq < 2; ++kq)
#pragma unroll
            for (int nh = 0; nh < 2; ++nh) {
                f16x8 v;
#pragma unroll
                for (int i = 0; i < 8; ++i)
                    v[i] = src[(kq * 16 + q * 8 + i) * HSTR + nh * 32 + t];
                ip[b][kq][nh] = v;
            }
    }
    // pB[s][i] = inp[w][z=t][k=s*16+q*8+i] — p-GEMM B-frags (wave w <-> batch w)
    f16x8 pB[4];
#pragma unroll
    for (int s = 0; s < 4; ++s)
        pB[s] = *(const f16x8*)(hL + w * 64 * HSTR + t * HSTR + s * 16 + q * 8);

    const int bglob = b0i + w;        // wave w <-> batch w (p-work)
    f16* pG = pW + (size_t)(bglob >> 5) * GSTR + (bglob & 31) * 8;
    const f16* H0 = Wf;
    const f16* H1 = Wf + 131072;
    f16* hA = hL + (bp * 2) * 64 * HSTR;
    f16* hB = hL + (bp * 2 + 1) * 64 * HSTR;
    f32x16 acc[2][2];
    float bve[16];

    // ---- Layer 0 (HJ=32) ----
    p_chunk(hL + w * 64 * HSTR, pB, pG + P0G, 0, t, q);     // p0 j 0..31
    h_gemm4<32>(H0 + g * 64 * 512, hA, hB, lane8, t, ip, acc);
    load_bias(b0v, bve, g, q);
    __syncthreads();                                   // B1: all h0 reads done
    epi4(acc, hA, hB, bve, g, t, q);                   // h1 (rows 0..63)
    __syncthreads();                                   // B2: h1 ready

    // ---- Layer 1 (HJ=64) ----
    p_chunk(hL + w * 64 * HSTR,             pB, pG + P1G, 0,  t, q);
    p_chunk(hL + w * 64 * HSTR + 32 * HSTR, pB, pG + P1G, 32, t, q);
    h_gemm4<64>(H1 + g * 128 * 512, hA, hB, lane8, t, ip, acc);
    load_bias(b1v, bve, g, q);
    __syncthreads();                                   // B3: all h1 reads done
    epi4(acc, hA, hB, bve, g, t, q);                   // h1 -> h2 in place
    __syncthreads();                                   // B4: h2 ready

    p_chunk(hL + w * 64 * HSTR,             pB, pG + P2G, 0,  t, q);
    p_chunk(hL + w * 64 * HSTR + 32 * HSTR, pB, pG + P2G, 32, t, q);
}

// =================== Kernel 2: out GEMMs (N = batch), R13 ==================
// Block = 512 thr (8 waves): mi = M-half, ki = K-quarter. B-frags 1KB
// wave-coalesced (fragment-ordered pW); mi-pair reads identical addresses
// (L1 share). Depth-8 prefetch ring. 4-way K partials reduced via 32KB LDS.
template <int KK>   // KK = total K-fragments (region0: 64, others: 128)
__device__ __forceinline__ void o_tile(const f16* __restrict__ Of,
                                       const f16* __restrict__ pBase,
                                       const float* __restrict__ biasp,
                                       float* __restrict__ out,
                                       float* __restrict__ rP,
                                       int bg, int colbase, int tid)
{
    const int w = tid >> 6, lane = tid & 63, t = lane & 31, q = lane >> 5;
    const int lane8 = lane * 8;
    const int mi = w & 1, ki = w >> 1;           // mi pairs adjacent -> B share
    const int SQ = KK / 4;                       // K-frags per wave (16 or 32)
    const f16* Ap = Of + (size_t)(mi * KK + ki * SQ) * 512 + lane8;
    const f16* Bp = pBase + (size_t)(ki * SQ) * 512 + lane8;

    f32x16 acc = zero16();
    f16x8 af[8], bf[8];
#pragma unroll
    for (int i = 0; i < 8; ++i) {
        af[i] = *(const f16x8*)(Ap + i * 512);
        bf[i] = *(const f16x8*)(Bp + i * 512);
    }
#pragma unroll 8
    for (int s = 0; s < SQ; ++s) {
        int idx = s & 7;
        f16x8 a = af[idx], b = bf[idx];
        int sn = s + 8 < SQ ? s + 8 : SQ - 1;    // clamped refill
        af[idx] = *(const f16x8*)(Ap + sn * 512);
        bf[idx] = *(const f16x8*)(Bp + sn * 512);
        acc = __builtin_amdgcn_mfma_f32_32x32x16_f16(a, b, acc, 0, 0, 0);
    }
#pragma unroll
    for (int r = 0; r < 16; ++r) {
        int m = mi * 32 + (r & 3) + 8 * (r >> 2) + 4 * q;
        rP[(ki * 32 + t) * 64 + m] = acc[r];
    }
    __syncthreads();
    // Combine: 512 thr x f32x4 = 2048 f32 (32 batches x 64 cols).
    {
        int n = tid >> 4;            // batch row 0..31
        int o = (tid & 15) * 4;      // col 0..60
        f32x4 v = *(const f32x4*)(rP + n * 64 + o);
#pragma unroll
        for (int k2 = 1; k2 < 4; ++k2) {
            f32x4 u = *(const f32x4*)(rP + (k2 * 32 + n) * 64 + o);
            v[0] += u[0]; v[1] += u[1]; v[2] += u[2]; v[3] += u[3];
        }
        f32x4 bb = *(const f32x4*)(biasp + o);
        v[0] += 64.0f * bb[0]; v[1] += 64.0f * bb[1];
        v[2] += 64.0f * bb[2]; v[3] += 64.0f * bb[3];
        *(f32x4*)(out + (size_t)(bg * 32 + n) * 256 + colbase + o) = v;
    }
}

__global__ void __launch_bounds__(512, 2)
cin_out(const f16* __restrict__ Wf, const f16* __restrict__ pW,
        const float* __restrict__ b0v, const float* __restrict__ b1v,
        const float* __restrict__ b2v, float* __restrict__ out)
{
    __shared__ __attribute__((aligned(16))) float rP[2 * 2 * 32 * 64];  // 32 KB
    const int tid = threadIdx.x;
    const int r  = blockIdx.x & 3;      // region
    const int bg = blockIdx.x >> 2;     // 32-batch group (64 of them)
    const f16* pGrp = pW + (size_t)bg * GSTR;
    if (r == 0)
        o_tile<64> (Wf + 65536,  pGrp + P0G, b0v + 64, out, rP, bg, 0,   tid);
    else if (r == 1)
        o_tile<128>(Wf + 262144, pGrp + P1G, b1v + 64, out, rP, bg, 64,  tid);
    else if (r == 2)
        o_tile<128>(Wf + 393216, pGrp + P2G, b2v,      out, rP, bg, 128, tid);
    else
        o_tile<128>(Wf + 524288, pGrp + P2G, b2v + 64, out, rP, bg, 192, tid);
}

extern "C" void kernel_launch(void* const* d_in, const int* in_sizes, int n_in,
                              void* d_out, int out_size, void* d_ws, size_t ws_size,
                              hipStream_t stream)
{
    const float* inp = (const float*)d_in[0];
    const float* W0  = (const float*)d_in[1];
    const float* b0  = (const float*)d_in[2];
    const float* W1  = (const float*)d_in[3];
    const float* b1  = (const float*)d_in[4];
    const float* W2  = (const float*)d_in[5];
    const float* b2  = (const float*)d_in[6];
    float* out = (float*)d_out;

    f16* Wf = (f16*)d_ws;             // 655360 f16 = 1.25 MB fragment-ordered
    f16* pW = Wf + 655360;            // 64 groups * 163840 f16 = 20 MB

    prep_frag<<<320, 256, 0, stream>>>(W0, W1, W2, Wf);
    cin_h<<<512, 256, 0, stream>>>(inp, Wf, pW, b0, b1);
    cin_out<<<256, 512, 0, stream>>>(Wf, pW, b0, b1, b2, out);
}

// Round 13
// 132.568 us; speedup vs baseline: 1.0600x; 1.0141x over previous
//
#include <hip/hip_runtime.h>

// xDeepFM CIN, MI355X (gfx950) — R21: R13 restored verbatim (strip R20 setprio).
// R20 post-mortem: setprio null-to-slightly-negative (cin_h 55.3->58.5,
// VGPR 112->108 schedule perturbation). Ledger: SIX cin_h restructures
// (R11 TLP, R14 VALU-share, R15 ILP-quad, R19 pipeline, R20 setprio) all
// lost to R10's compiler-scheduled 2-waves/SIMD x 8-MFMA-window structure.
// cin_h ~55us = MFMA 21.2us floor + VALU ~20us at ~78% combined coverage.
// cin_out ~7us (post R13 coalescing) ~= HBM floor; prep ~6us; residual
// ~45us is kernel-boundary + harness fixed cost (R18: deleting a kernel
// + 40MB traffic moved it only ~13us). This is the best verified config:
// 132.3us, measured twice (R4, R9).

typedef _Float16 f16;
typedef _Float16 f16x4 __attribute__((ext_vector_type(4)));
typedef _Float16 f16x8 __attribute__((ext_vector_type(8)));
typedef float f32x4 __attribute__((ext_vector_type(4)));
typedef float f32x16 __attribute__((ext_vector_type(16)));

#define HSTR 72      // h LDS row stride (f16): 144B = 9*16B, b128-aligned
#define GSTR 163840  // pW per-32-batch-group stride (f16): 320 frags * 512
#define P0G  0       // p0 frags [0,64)   within group
#define P1G  32768   // p1 frags [0,128)  within group
#define P2G  98304   // p2 frags [0,128)  within group

__device__ __forceinline__ f32x16 zero16() {
    f32x16 v;
#pragma unroll
    for (int i = 0; i < 16; ++i) v[i] = 0.0f;
    return v;
}

// ---------------- prep: W (fp32 row-major) -> f16 fragment-ordered ----------
// Fragment (mc, kk) = 512 f16; element lane*8+i =
//   W[rbase + mc*32 + (lane&31)][kk*16 + (lane>>5)*8 + i]
// Regions (f16 offsets): H0@0 (W0 r0..63, KK=64) | O0@65536 (W0 r64..127) |
// H1@131072 (W1 r0..63, KK=128) | O1@262144 (W1 r64..127) | O2@393216 (W2 all).
__global__ void __launch_bounds__(256)
prep_frag(const float* __restrict__ W0, const float* __restrict__ W1,
          const float* __restrict__ W2, f16* __restrict__ dst)
{
    int g = (blockIdx.x * 256 + threadIdx.x) * 8;    // grid = 320
    const float* src; int base, KK, rbase;
    if (g < 65536)       { src = W0; base = 0;      KK = 64;  rbase = 0;  }
    else if (g < 131072) { src = W0; base = 65536;  KK = 64;  rbase = 64; }
    else if (g < 262144) { src = W1; base = 131072; KK = 128; rbase = 0;  }
    else if (g < 393216) { src = W1; base = 262144; KK = 128; rbase = 64; }
    else                 { src = W2; base = 393216; KK = 128; rbase = 0;  }
    int local = g - base;
    int frag  = local >> 9;
    int lane  = (local >> 3) & 63;
    int kk    = frag % KK;
    int mc    = frag / KK;
    int row   = rbase + mc * 32 + (lane & 31);
    int col   = kk * 16 + (lane >> 5) * 8;
    int IC    = KK * 16;
    const float* s = src + (size_t)row * IC + col;
    f16x8 o;
#pragma unroll
    for (int i = 0; i < 8; ++i) o[i] = (f16)s[i];
    *(f16x8*)(dst + g) = o;
}

// ---- p-chunk: P rows [jb, jb+32) of one batch (M=32 j, N=32 z, K=64) ------
// Writes fragment-ordered: pdst = groupbase + regionoff + (b&31)*8.
__device__ __forceinline__ void p_chunk(const f16* __restrict__ hrows,
                                        const f16x8 (&pB)[4],
                                        f16* __restrict__ pdst, int jb,
                                        int t, int q)
{
    f32x16 acc = zero16();
#pragma unroll
    for (int s = 0; s < 4; ++s) {
        f16x8 a = *(const f16x8*)(hrows + t * HSTR + s * 16 + q * 8);
        acc = __builtin_amdgcn_mfma_f32_32x32x16_f16(a, pB[s], acc, 0, 0, 0);
    }
#pragma unroll
    for (int r = 0; r < 16; ++r) {
        int j = jb + (r & 3) + 8 * (r >> 2) + 4 * q;
        int f = j * 2 + (t >> 4);
        pdst[f * 512 + ((t >> 3) & 1) * 256 + (t & 7)] = (f16)acc[r];
    }
}

// ---- h-GEMM: rows [g*32,+32), ALL 64 cols, TWO batches ---------------------
// Per j: 2 W-frag loads feed 8 MFMAs (258 SIMD-cyc window > L2 latency).
// Ping-pong depth-2 (j, j+1 resident; refill j+2).
template <int HJ>
__device__ __forceinline__ void h_gemm4(const f16* __restrict__ Hf,
                                        const f16* __restrict__ h0,
                                        const f16* __restrict__ h1,
                                        int lane8, int t,
                                        const f16x8 (&ip)[2][2][2],   // [b][kq][nh]
                                        f32x16 (&acc)[2][2])          // [b][nh]
{
    acc[0][0] = zero16(); acc[0][1] = zero16();
    acc[1][0] = zero16(); acc[1][1] = zero16();
    const f16* Wp = Hf + lane8;
    f16x8 wf[2][2];   // [phase][kq]
    f16   sc[2][4];   // [phase][b*2+nh]
#pragma unroll
    for (int ph = 0; ph < 2; ++ph) {
        wf[ph][0] = *(const f16x8*)(Wp + (ph * 2 + 0) * 512);
        wf[ph][1] = *(const f16x8*)(Wp + (ph * 2 + 1) * 512);
        sc[ph][0] = h0[ph * HSTR + t];
        sc[ph][1] = h0[ph * HSTR + 32 + t];
        sc[ph][2] = h1[ph * HSTR + t];
        sc[ph][3] = h1[ph * HSTR + 32 + t];
    }
    for (int jj = 0; jj < HJ; jj += 2) {
#pragma unroll
        for (int ph = 0; ph < 2; ++ph) {
            f16x8 w0 = wf[ph][0], w1 = wf[ph][1];
            f16 s00 = sc[ph][0], s01 = sc[ph][1];
            f16 s10 = sc[ph][2], s11 = sc[ph][3];
            int jn = jj + ph + 2;
            if (jn > HJ - 1) jn = HJ - 1;              // clamped refill
            wf[ph][0] = *(const f16x8*)(Wp + (jn * 2 + 0) * 512);
            wf[ph][1] = *(const f16x8*)(Wp + (jn * 2 + 1) * 512);
            sc[ph][0] = h0[jn * HSTR + t];
            sc[ph][1] = h0[jn * HSTR + 32 + t];
            sc[ph][2] = h1[jn * HSTR + t];
            sc[ph][3] = h1[jn * HSTR + 32 + t];
            acc[0][0] = __builtin_amdgcn_mfma_f32_32x32x16_f16(w0, ip[0][0][0] * s00, acc[0][0], 0, 0, 0);
            acc[0][0] = __builtin_amdgcn_mfma_f32_32x32x16_f16(w1, ip[0][1][0] * s00, acc[0][0], 0, 0, 0);
            acc[0][1] = __builtin_amdgcn_mfma_f32_32x32x16_f16(w0, ip[0][0][1] * s01, acc[0][1], 0, 0, 0);
            acc[0][1] = __builtin_amdgcn_mfma_f32_32x32x16_f16(w1, ip[0][1][1] * s01, acc[0][1], 0, 0, 0);
            acc[1][0] = __builtin_amdgcn_mfma_f32_32x32x16_f16(w0, ip[1][0][0] * s10, acc[1][0], 0, 0, 0);
            acc[1][0] = __builtin_amdgcn_mfma_f32_32x32x16_f16(w1, ip[1][1][0] * s10, acc[1][0], 0, 0, 0);
            acc[1][1] = __builtin_amdgcn_mfma_f32_32x32x16_f16(w0, ip[1][0][1] * s11, acc[1][1], 0, 0, 0);
            acc[1][1] = __builtin_amdgcn_mfma_f32_32x32x16_f16(w1, ip[1][1][1] * s11, acc[1][1], 0, 0, 0);
        }
    }
}

__device__ __forceinline__ void load_bias(const float* __restrict__ bl,
                                          float (&bve)[16], int g, int q)
{
#pragma unroll
    for (int r = 0; r < 16; ++r)
        bve[r] = bl[g * 32 + (r & 3) + 8 * (r >> 2) + 4 * q];
}

// Write h_{l+1} rows [g*32,+32), all 64 cols, both batches.
__device__ __forceinline__ void epi4(const f32x16 (&acc)[2][2],
                                     f16* __restrict__ h0d, f16* __restrict__ h1d,
                                     const float (&bve)[16], int g, int t, int q)
{
#pragma unroll
    for (int r = 0; r < 16; ++r) {
        int row = g * 32 + (r & 3) + 8 * (r >> 2) + 4 * q;
        h0d[row * HSTR + t]      = (f16)(acc[0][0][r] + bve[r]);
        h0d[row * HSTR + 32 + t] = (f16)(acc[0][1][r] + bve[r]);
        h1d[row * HSTR + t]      = (f16)(acc[1][0][r] + bve[r]);
        h1d[row * HSTR + 32 + t] = (f16)(acc[1][1][r] + bve[r]);
    }
}

// =================== Kernel 1: h-chain + p-vectors =========================
__global__ void __launch_bounds__(256, 2)
cin_h(const float* __restrict__ inp, const f16* __restrict__ Wf,
      f16* __restrict__ pW,
      const float* __restrict__ b0v, const float* __restrict__ b1v)
{
    __shared__ __attribute__((aligned(16))) f16 hL[4 * 64 * HSTR];  // 36864 B

    const int tid   = threadIdx.x;
    const int w     = tid >> 6;
    const int lane  = tid & 63;
    const int t     = lane & 31;
    const int q     = lane >> 5;
    const int lane8 = lane * 8;
    const int bp    = w & 1;          // batch-pair (local batches bp*2, bp*2+1)
    const int g     = w >> 1;         // row-half
    const int b0i   = blockIdx.x * 4;

    // Stage: 4 batches x 32 z-rows of inp (f32 coalesced) -> hL rows 0..31.
#pragma unroll
    for (int it = 0; it < 8; ++it) {
        int idx = it * 1024 + tid * 4;
        int b = idx >> 11, rem = idx & 2047;
        int z = rem >> 6, k = rem & 63;
        f32x4 v = *(const f32x4*)(inp + (size_t)(b0i + b) * 2048 + rem);
        f16x4 h4;
        h4[0] = (f16)v[0]; h4[1] = (f16)v[1]; h4[2] = (f16)v[2]; h4[3] = (f16)v[3];
        *(f16x4*)(hL + b * 64 * HSTR + z * HSTR + k) = h4;
    }
    __syncthreads();                                   // B0: h0 (=inp) ready

    // ip[b][kq][nh][i] = inp[bp*2+b][z=kq*16+q*8+i][nh*32+t]
    f16x8 ip[2][2][2];
#pragma unroll
    for (int b = 0; b < 2; ++b) {
        const f16* src = hL + (bp * 2 + b) * 64 * HSTR;
#pragma unroll
        for (int kq = 0; kq < 2; ++kq)
#pragma unroll
            for (int nh = 0; nh < 2; ++nh) {
                f16x8 v;
#pragma unroll
                for (int i = 0; i < 8; ++i)
                    v[i] = src[(kq * 16 + q * 8 + i) * HSTR + nh * 32 + t];
                ip[b][kq][nh] = v;
            }
    }
    // pB[s][i] = inp[w][z=t][k=s*16+q*8+i] — p-GEMM B-frags (wave w <-> batch w)
    f16x8 pB[4];
#pragma unroll
    for (int s = 0; s < 4; ++s)
        pB[s] = *(const f16x8*)(hL + w * 64 * HSTR + t * HSTR + s * 16 + q * 8);

    const int bglob = b0i + w;        // wave w <-> batch w (p-work)
    f16* pG = pW + (size_t)(bglob >> 5) * GSTR + (bglob & 31) * 8;
    const f16* H0 = Wf;
    const f16* H1 = Wf + 131072;
    f16* hA = hL + (bp * 2) * 64 * HSTR;
    f16* hB = hL + (bp * 2 + 1) * 64 * HSTR;
    f32x16 acc[2][2];
    float bve[16];

    // ---- Layer 0 (HJ=32) ----
    p_chunk(hL + w * 64 * HSTR, pB, pG + P0G, 0, t, q);     // p0 j 0..31
    h_gemm4<32>(H0 + g * 64 * 512, hA, hB, lane8, t, ip, acc);
    load_bias(b0v, bve, g, q);
    __syncthreads();                                   // B1: all h0 reads done
    epi4(acc, hA, hB, bve, g, t, q);                   // h1 (rows 0..63)
    __syncthreads();                                   // B2: h1 ready

    // ---- Layer 1 (HJ=64) ----
    p_chunk(hL + w * 64 * HSTR,             pB, pG + P1G, 0,  t, q);
    p_chunk(hL + w * 64 * HSTR + 32 * HSTR, pB, pG + P1G, 32, t, q);
    h_gemm4<64>(H1 + g * 128 * 512, hA, hB, lane8, t, ip, acc);
    load_bias(b1v, bve, g, q);
    __syncthreads();                                   // B3: all h1 reads done
    epi4(acc, hA, hB, bve, g, t, q);                   // h1 -> h2 in place
    __syncthreads();                                   // B4: h2 ready

    p_chunk(hL + w * 64 * HSTR,             pB, pG + P2G, 0,  t, q);
    p_chunk(hL + w * 64 * HSTR + 32 * HSTR, pB, pG + P2G, 32, t, q);
}

// =================== Kernel 2: out GEMMs (N = batch), R13 ==================
// Block = 512 thr (8 waves): mi = M-half, ki = K-quarter. B-frags 1KB
// wave-coalesced (fragment-ordered pW); mi-pair reads identical addresses
// (L1 share). Depth-8 prefetch ring. 4-way K partials reduced via 32KB LDS.
template <int KK>   // KK = total K-fragments (region0: 64, others: 128)
__device__ __forceinline__ void o_tile(const f16* __restrict__ Of,
                                       const f16* __restrict__ pBase,
                                       const float* __restrict__ biasp,
                                       float* __restrict__ out,
                                       float* __restrict__ rP,
                                       int bg, int colbase, int tid)
{
    const int w = tid >> 6, lane = tid & 63, t = lane & 31, q = lane >> 5;
    const int lane8 = lane * 8;
    const int mi = w & 1, ki = w >> 1;           // mi pairs adjacent -> B share
    const int SQ = KK / 4;                       // K-frags per wave (16 or 32)
    const f16* Ap = Of + (size_t)(mi * KK + ki * SQ) * 512 + lane8;
    const f16* Bp = pBase + (size_t)(ki * SQ) * 512 + lane8;

    f32x16 acc = zero16();
    f16x8 af[8], bf[8];
#pragma unroll
    for (int i = 0; i < 8; ++i) {
        af[i] = *(const f16x8*)(Ap + i * 512);
        bf[i] = *(const f16x8*)(Bp + i * 512);
    }
#pragma unroll 8
    for (int s = 0; s < SQ; ++s) {
        int idx = s & 7;
        f16x8 a = af[idx], b = bf[idx];
        int sn = s + 8 < SQ ? s + 8 : SQ - 1;    // clamped refill
        af[idx] = *(const f16x8*)(Ap + sn * 512);
        bf[idx] = *(const f16x8*)(Bp + sn * 512);
        acc = __builtin_amdgcn_mfma_f32_32x32x16_f16(a, b, acc, 0, 0, 0);
    }
#pragma unroll
    for (int r = 0; r < 16; ++r) {
        int m = mi * 32 + (r & 3) + 8 * (r >> 2) + 4 * q;
        rP[(ki * 32 + t) * 64 + m] = acc[r];
    }
    __syncthreads();
    // Combine: 512 thr x f32x4 = 2048 f32 (32 batches x 64 cols).
    {
        int n = tid >> 4;            // batch row 0..31
        int o = (tid & 15) * 4;      // col 0..60
        f32x4 v = *(const f32x4*)(rP + n * 64 + o);
#pragma unroll
        for (int k2 = 1; k2 < 4; ++k2) {
            f32x4 u = *(const f32x4*)(rP + (k2 * 32 + n) * 64 + o);
            v[0] += u[0]; v[1] += u[1]; v[2] += u[2]; v[3] += u[3];
        }
        f32x4 bb = *(const f32x4*)(biasp + o);
        v[0] += 64.0f * bb[0]; v[1] += 64.0f * bb[1];
        v[2] += 64.0f * bb[2]; v[3] += 64.0f * bb[3];
        *(f32x4*)(out + (size_t)(bg * 32 + n) * 256 + colbase + o) = v;
    }
}

__global__ void __launch_bounds__(512, 2)
cin_out(const f16* __restrict__ Wf, const f16* __restrict__ pW,
        const float* __restrict__ b0v, const float* __restrict__ b1v,
        const float* __restrict__ b2v, float* __restrict__ out)
{
    __shared__ __attribute__((aligned(16))) float rP[4 * 32 * 64];  // 32 KB
    const int tid = threadIdx.x;
    const int r  = blockIdx.x & 3;      // region
    const int bg = blockIdx.x >> 2;     // 32-batch group (64 of them)
    const f16* pGrp = pW + (size_t)bg * GSTR;
    if (r == 0)
        o_tile<64> (Wf + 65536,  pGrp + P0G, b0v + 64, out, rP, bg, 0,   tid);
    else if (r == 1)
        o_tile<128>(Wf + 262144, pGrp + P1G, b1v + 64, out, rP, bg, 64,  tid);
    else if (r == 2)
        o_tile<128>(Wf + 393216, pGrp + P2G, b2v,      out, rP, bg, 128, tid);
    else
        o_tile<128>(Wf + 524288, pGrp + P2G, b2v + 64, out, rP, bg, 192, tid);
}

extern "C" void kernel_launch(void* const* d_in, const int* in_sizes, int n_in,
                              void* d_out, int out_size, void* d_ws, size_t ws_size,
                              hipStream_t stream)
{
    const float* inp = (const float*)d_in[0];
    const float* W0  = (const float*)d_in[1];
    const float* b0  = (const float*)d_in[2];
    const float* W1  = (const float*)d_in[3];
    const float* b1  = (const float*)d_in[4];
    const float* W2  = (const float*)d_in[5];
    const float* b2  = (const float*)d_in[6];
    float* out = (float*)d_out;

    f16* Wf = (f16*)d_ws;             // 655360 f16 = 1.25 MB fragment-ordered
    f16* pW = Wf + 655360;            // 64 groups * 163840 f16 = 20 MB

    prep_frag<<<320, 256, 0, stream>>>(W0, W1, W2, Wf);
    cin_h<<<512, 256, 0, stream>>>(inp, Wf, pW, b0, b1);
    cin_out<<<256, 512, 0, stream>>>(Wf, pW, b0, b1, b2, out);
}